// Round 2
// baseline (142.176 us; speedup 1.0000x reference)
//
#include <hip/hip_runtime.h>
#include <hip/hip_bf16.h>

#define L_N 64
#define T_N 8192
#define K_N 128
#define N_N 128

typedef __attribute__((ext_vector_type(8))) short short8;   // 8 bf16 = 4 VGPR
typedef __attribute__((ext_vector_type(4))) float f32x4;    // MFMA acc

__device__ __forceinline__ unsigned short f2bf(float f) {
    union { float f; unsigned u; } c; c.f = f;
    return (unsigned short)((c.u + 0x7fffu + ((c.u >> 16) & 1u)) >> 16);  // RNE
}

// Prepass: w [L][K][N] fp32 -> pre-fragmented bf16  wf[l][ni][kk][lane][j]
// so the main kernel's A-fragment load is ONE coalesced dwordx4 per (ni,kk):
//   element (l,ni,kk,lane,j) = w[l][ kk*32 + (lane>>4)*8 + j ][ ni*16 + (lane&15) ]
__global__ __launch_bounds__(256) void wfrag_kernel(const float* __restrict__ w,
                                                    unsigned short* __restrict__ wf) {
    __shared__ float lds[K_N * 129];            // +1 pad, 66 KB
    const int l = blockIdx.x;
    const float* wl = w + (size_t)l * (K_N * N_N);
    const int tid = threadIdx.x;
    #pragma unroll
    for (int i = 0; i < 16; ++i) {
        int f = i * 256 + tid;                  // float4 idx, coalesced
        float4 v = ((const float4*)wl)[f];
        int k = f >> 5, n = (f & 31) * 4;
        lds[k * 129 + n + 0] = v.x;
        lds[k * 129 + n + 1] = v.y;
        lds[k * 129 + n + 2] = v.z;
        lds[k * 129 + n + 3] = v.w;
    }
    __syncthreads();
    unsigned short* o = wf + (size_t)l * (N_N * K_N);
    #pragma unroll
    for (int c = 0; c < 16; ++c) {
        int chunk = c * 256 + tid;              // ushort4 idx, 4096/layer, coalesced write
        int j0   = (chunk & 1) * 4;
        int lane = (chunk >> 1) & 63;
        int kk   = (chunk >> 7) & 3;
        int ni   = chunk >> 9;
        int n  = ni * 16 + (lane & 15);
        int kb = kk * 32 + (lane >> 4) * 8 + j0;
        ushort4 ov;
        ov.x = f2bf(lds[(kb + 0) * 129 + n]);
        ov.y = f2bf(lds[(kb + 1) * 129 + n]);
        ov.z = f2bf(lds[(kb + 2) * 129 + n]);
        ov.w = f2bf(lds[(kb + 3) * 129 + n]);
        ((ushort4*)o)[chunk] = ov;
    }
}

// Main: fully streaming, NO LDS, NO barriers. 4 waves/block, each wave owns a
// disjoint 32-row strip x all 128 cols (x has zero reuse -> direct global loads).
// A = w fragment (free dim = out col n), B = x fragment (free dim = out row t):
//   lane(lr,lg) reg j  ->  out[t = strip+mi*16+lr][n = ni*16+lg*4+j]
// -> float4 epilogue stores with fused bias.
__global__ __launch_bounds__(256, 3) void gl_kernel(const float* __restrict__ x,
                                                    const unsigned short* __restrict__ wf,
                                                    const float* __restrict__ bias,
                                                    float* __restrict__ out) {
    const int tid  = threadIdx.x;
    const int lane = tid & 63;
    const int wid  = tid >> 6;
    const int lr   = lane & 15;
    const int lg   = lane >> 4;

    // bijective XCD swizzle: 4096 blocks, 8 XCDs -> each XCD gets 8 whole layers
    const int bid = blockIdx.x;
    const int swz = (bid & 7) * 512 + (bid >> 3);
    const int l    = swz >> 6;
    const int tile = swz & 63;
    const int strip = tile * 128 + wid * 32;    // this wave's first row

    const float* xg = x + ((size_t)l * T_N + strip) * K_N;
    const unsigned short* wl = wf + (size_t)l * (N_N * K_N);

    f32x4 acc[2][8];
    #pragma unroll
    for (int mi = 0; mi < 2; ++mi)
        #pragma unroll
        for (int ni = 0; ni < 8; ++ni)
            acc[mi][ni] = (f32x4){0.f, 0.f, 0.f, 0.f};

    #pragma unroll
    for (int kk = 0; kk < 4; ++kk) {
        // x fragments: 16 rows x 128B lines, fully consumed
        short8 xb[2];
        #pragma unroll
        for (int mi = 0; mi < 2; ++mi) {
            const float* p = xg + (size_t)(mi * 16 + lr) * K_N + kk * 32 + lg * 8;
            const float4 u0 = *(const float4*)p;
            const float4 u1 = *(const float4*)(p + 4);
            union { unsigned short s[8]; short8 v; } pk;
            pk.s[0] = f2bf(u0.x); pk.s[1] = f2bf(u0.y);
            pk.s[2] = f2bf(u0.z); pk.s[3] = f2bf(u0.w);
            pk.s[4] = f2bf(u1.x); pk.s[5] = f2bf(u1.y);
            pk.s[6] = f2bf(u1.z); pk.s[7] = f2bf(u1.w);
            xb[mi] = pk.v;
        }
        // w fragments: one coalesced 1KB dwordx4 per (ni,kk), L2-resident
        short8 wv[8];
        #pragma unroll
        for (int ni = 0; ni < 8; ++ni)
            wv[ni] = *(const short8*)(wl + ((size_t)(ni * 4 + kk) * 64 + lane) * 8);
        #pragma unroll
        for (int ni = 0; ni < 8; ++ni) {
            acc[0][ni] = __builtin_amdgcn_mfma_f32_16x16x32_bf16(wv[ni], xb[0], acc[0][ni], 0, 0, 0);
            acc[1][ni] = __builtin_amdgcn_mfma_f32_16x16x32_bf16(wv[ni], xb[1], acc[1][ni], 0, 0, 0);
        }
    }

    // epilogue: fused bias, float4 stores (lane's 4 regs = 4 consecutive cols)
    const float* bl = bias + l * N_N;
    float* og = out + ((size_t)l * T_N + strip) * N_N;
    #pragma unroll
    for (int ni = 0; ni < 8; ++ni) {
        const float4 bv = *(const float4*)(bl + ni * 16 + lg * 4);
        #pragma unroll
        for (int mi = 0; mi < 2; ++mi) {
            float4 r;
            r.x = acc[mi][ni][0] + bv.x;
            r.y = acc[mi][ni][1] + bv.y;
            r.z = acc[mi][ni][2] + bv.z;
            r.w = acc[mi][ni][3] + bv.w;
            *(float4*)(og + (size_t)(mi * 16 + lr) * N_N + ni * 16 + lg * 4) = r;
        }
    }
}

extern "C" void kernel_launch(void* const* d_in, const int* in_sizes, int n_in,
                              void* d_out, int out_size, void* d_ws, size_t ws_size,
                              hipStream_t stream) {
    const float* x = (const float*)d_in[0];
    const float* w = (const float*)d_in[1];
    const float* b = (const float*)d_in[2];
    float* out = (float*)d_out;
    unsigned short* wf = (unsigned short*)d_ws;   // 2 MB scratch, rewritten every call

    wfrag_kernel<<<L_N, 256, 0, stream>>>(w, wf);
    gl_kernel<<<L_N * (T_N / 128), 256, 0, stream>>>(x, wf, b, out);
}

// Round 3
// 134.072 us; speedup vs baseline: 1.0604x; 1.0604x over previous
//
#include <hip/hip_runtime.h>
#include <hip/hip_bf16.h>

#define L_N 64
#define T_N 8192
#define K_N 128
#define N_N 128
#define BM  128

typedef __attribute__((ext_vector_type(8))) short short8;   // 8 bf16 = 4 VGPR
typedef __attribute__((ext_vector_type(4))) float f32x4;    // MFMA acc

__device__ __forceinline__ unsigned short f2bf(float f) {
    union { float f; unsigned u; } c; c.f = f;
    return (unsigned short)((c.u + 0x7fffu + ((c.u >> 16) & 1u)) >> 16);  // RNE
}

// Prepass: w [L][K][N] fp32 -> pre-fragmented bf16  wf[l][ni][kk][lane][j]
//   element (l,ni,kk,lane,j) = w[l][ kk*32 + (lane>>4)*8 + j ][ ni*16 + (lane&15) ]
// so the main kernel's A-fragment load is ONE coalesced 1KB dwordx4 per (ni,kk).
__global__ __launch_bounds__(256) void wfrag_kernel(const float* __restrict__ w,
                                                    unsigned short* __restrict__ wf) {
    __shared__ float lds[K_N * 129];            // +1 pad, 66 KB
    const int l = blockIdx.x;
    const float* wl = w + (size_t)l * (K_N * N_N);
    const int tid = threadIdx.x;
    #pragma unroll
    for (int i = 0; i < 16; ++i) {
        int f = i * 256 + tid;                  // float4 idx, coalesced
        float4 v = ((const float4*)wl)[f];
        int k = f >> 5, n = (f & 31) * 4;
        lds[k * 129 + n + 0] = v.x;
        lds[k * 129 + n + 1] = v.y;
        lds[k * 129 + n + 2] = v.z;
        lds[k * 129 + n + 3] = v.w;
    }
    __syncthreads();
    unsigned short* o = wf + (size_t)l * (N_N * K_N);
    #pragma unroll
    for (int c = 0; c < 16; ++c) {
        int chunk = c * 256 + tid;              // ushort4 idx, coalesced write
        int j0   = (chunk & 1) * 4;
        int lane = (chunk >> 1) & 63;
        int kk   = (chunk >> 7) & 3;
        int ni   = chunk >> 9;
        int n  = ni * 16 + (lane & 15);
        int kb = kk * 32 + (lane >> 4) * 8 + j0;
        ushort4 ov;
        ov.x = f2bf(lds[(kb + 0) * 129 + n]);
        ov.y = f2bf(lds[(kb + 1) * 129 + n]);
        ov.z = f2bf(lds[(kb + 2) * 129 + n]);
        ov.w = f2bf(lds[(kb + 3) * 129 + n]);
        ((ushort4*)o)[chunk] = ov;
    }
}

// Main: x staged to LDS (flat coalesced fp32 reads -> bf16 -> XOR-swizzled LDS);
// w fragments straight from L2-resident wf; A=w / B=x operand order so each
// lane's 4 acc regs = 4 consecutive out columns -> float4 fused-bias stores.
// 32 KB LDS -> 4 blocks/CU for cross-block load/compute/store overlap.
__global__ __launch_bounds__(256, 4) void gl_kernel(const float* __restrict__ x,
                                                    const unsigned short* __restrict__ wf,
                                                    const float* __restrict__ bias,
                                                    float* __restrict__ out) {
    __shared__ unsigned short xs[BM * K_N];     // 32 KB, XOR-swizzled bf16

    const int tid  = threadIdx.x;
    const int lane = tid & 63;
    const int wid  = tid >> 6;
    const int lr   = lane & 15;
    const int lg   = lane >> 4;

    // bijective XCD swizzle: 4096 blocks, 8 XCDs -> each XCD gets 8 whole layers
    const int bid = blockIdx.x;
    const int swz = (bid & 7) * 512 + (bid >> 3);
    const int l    = swz >> 6;
    const int tile = swz & 63;
    const float* xg = x + ((size_t)l * T_N + tile * BM) * K_N;

    // stage x tile: flat-contiguous float4 reads (1KB/instr, lines fully
    // consumed), convert to bf16, swizzled 8B LDS writes (R1-verified, 0 conflicts)
    #pragma unroll
    for (int i = 0; i < 16; ++i) {
        int f = i * 256 + tid;                  // float4 index
        const float4 v = ((const float4*)xg)[f];
        int row = f >> 5;
        int kc  = (f & 31) * 4;
        union { unsigned short s[4]; unsigned long long u; } p;
        p.s[0] = f2bf(v.x); p.s[1] = f2bf(v.y); p.s[2] = f2bf(v.z); p.s[3] = f2bf(v.w);
        int us = (row * K_N + kc) ^ ((row & 7) << 3);
        *(unsigned long long*)&xs[us] = p.u;
    }

    const unsigned short* wl = wf + (size_t)l * (N_N * K_N);
    __syncthreads();

    f32x4 acc[2][8];
    #pragma unroll
    for (int mi = 0; mi < 2; ++mi)
        #pragma unroll
        for (int ni = 0; ni < 8; ++ni)
            acc[mi][ni] = (f32x4){0.f, 0.f, 0.f, 0.f};

    const int strip = wid * 32;                 // this wave's rows within the tile
    #pragma unroll
    for (int kk = 0; kk < 4; ++kk) {
        const int kbase = kk * 32 + lg * 8;
        short8 xb[2];
        #pragma unroll
        for (int mi = 0; mi < 2; ++mi) {
            int row = strip + mi * 16 + lr;
            xb[mi] = *(const short8*)&xs[(row * K_N + kbase) ^ ((row & 7) << 3)];
        }
        short8 wv[8];
        #pragma unroll
        for (int ni = 0; ni < 8; ++ni)
            wv[ni] = *(const short8*)(wl + ((size_t)(ni * 4 + kk) * 64 + lane) * 8);
        #pragma unroll
        for (int ni = 0; ni < 8; ++ni) {
            acc[0][ni] = __builtin_amdgcn_mfma_f32_16x16x32_bf16(wv[ni], xb[0], acc[0][ni], 0, 0, 0);
            acc[1][ni] = __builtin_amdgcn_mfma_f32_16x16x32_bf16(wv[ni], xb[1], acc[1][ni], 0, 0, 0);
        }
    }

    // epilogue: fused bias, float4 stores
    const float* bl = bias + l * N_N;
    float* og = out + ((size_t)l * T_N + tile * BM + strip) * N_N;
    #pragma unroll
    for (int ni = 0; ni < 8; ++ni) {
        const float4 bv = *(const float4*)(bl + ni * 16 + lg * 4);
        #pragma unroll
        for (int mi = 0; mi < 2; ++mi) {
            float4 r;
            r.x = acc[mi][ni][0] + bv.x;
            r.y = acc[mi][ni][1] + bv.y;
            r.z = acc[mi][ni][2] + bv.z;
            r.w = acc[mi][ni][3] + bv.w;
            *(float4*)(og + (size_t)(mi * 16 + lr) * N_N + ni * 16 + lg * 4) = r;
        }
    }
}

extern "C" void kernel_launch(void* const* d_in, const int* in_sizes, int n_in,
                              void* d_out, int out_size, void* d_ws, size_t ws_size,
                              hipStream_t stream) {
    const float* x = (const float*)d_in[0];
    const float* w = (const float*)d_in[1];
    const float* b = (const float*)d_in[2];
    float* out = (float*)d_out;
    unsigned short* wf = (unsigned short*)d_ws;   // 2 MB scratch, rewritten every call

    wfrag_kernel<<<L_N, 256, 0, stream>>>(w, wf);
    gl_kernel<<<L_N * (T_N / BM), 256, 0, stream>>>(x, wf, b, out);
}

// Round 4
// 110.120 us; speedup vs baseline: 1.2911x; 1.2175x over previous
//
#include <hip/hip_runtime.h>
#include <hip/hip_bf16.h>

#define L_N 64
#define T_N 8192
#define K_N 128
#define N_N 128
#define BM  128

typedef __attribute__((ext_vector_type(8))) short short8;   // 8 bf16 = 4 VGPR
typedef __attribute__((ext_vector_type(4))) float f32x4;    // MFMA acc

__device__ __forceinline__ unsigned short f2bf(float f) {
    union { float f; unsigned u; } c; c.f = f;
    return (unsigned short)((c.u + 0x7fffu + ((c.u >> 16) & 1u)) >> 16);  // RNE
}

// Prepass: w [L][K][N] fp32 -> pre-fragmented bf16  wf[l][ni][kk][lane][j]
//   element (l,ni,kk,lane,j) = w[l][ kk*32 + (lane>>4)*8 + j ][ ni*16 + (lane&15) ]
// (verified R2/R3). Main kernel stages wf[l] to LDS as a LINEAR 32KB copy;
// fragment reads are then lane-consecutive 16B -> conflict-free, no repack.
__global__ __launch_bounds__(256) void wfrag_kernel(const float* __restrict__ w,
                                                    unsigned short* __restrict__ wf) {
    __shared__ float lds[K_N * 129];            // +1 pad, 66 KB
    const int l = blockIdx.x;
    const float* wl = w + (size_t)l * (K_N * N_N);
    const int tid = threadIdx.x;
    #pragma unroll
    for (int i = 0; i < 16; ++i) {
        int f = i * 256 + tid;                  // float4 idx, coalesced
        float4 v = ((const float4*)wl)[f];
        int k = f >> 5, n = (f & 31) * 4;
        lds[k * 129 + n + 0] = v.x;
        lds[k * 129 + n + 1] = v.y;
        lds[k * 129 + n + 2] = v.z;
        lds[k * 129 + n + 3] = v.w;
    }
    __syncthreads();
    unsigned short* o = wf + (size_t)l * (N_N * K_N);
    #pragma unroll
    for (int c = 0; c < 16; ++c) {
        int chunk = c * 256 + tid;              // ushort4 idx, coalesced write
        int j0   = (chunk & 1) * 4;
        int lane = (chunk >> 1) & 63;
        int kk   = (chunk >> 7) & 3;
        int ni   = chunk >> 9;
        int n  = ni * 16 + (lane & 15);
        int kb = kk * 32 + (lane >> 4) * 8 + j0;
        ushort4 ov;
        ov.x = f2bf(lds[(kb + 0) * 129 + n]);
        ov.y = f2bf(lds[(kb + 1) * 129 + n]);
        ov.z = f2bf(lds[(kb + 2) * 129 + n]);
        ov.w = f2bf(lds[(kb + 3) * 129 + n]);
        ((ushort4*)o)[chunk] = ov;
    }
}

// Main: 512 threads (8 waves) per block -> 2 blocks/CU at 64KB LDS = 16 waves/CU
// (2x R1's TLP). Both operands in LDS (R1's winning data path). Epilogue recycles
// the 64KB LDS as a transpose buffer -> fully-contiguous 1KB/wave float4 stores.
__global__ __launch_bounds__(512, 4) void gl_kernel(const float* __restrict__ x,
                                                    const unsigned short* __restrict__ wf,
                                                    const float* __restrict__ bias,
                                                    float* __restrict__ out) {
    __shared__ __align__(16) char smem[65536];
    unsigned short* xs  = (unsigned short*)smem;            // 32KB x bf16, XOR-swizzled
    unsigned short* wsh = (unsigned short*)(smem + 32768);  // 32KB w frag-ordered (linear)

    const int tid  = threadIdx.x;
    const int lane = tid & 63;
    const int wid  = tid >> 6;                  // 8 waves, wave owns 16 rows x 128 cols
    const int lr   = lane & 15;
    const int lg   = lane >> 4;

    const int bid  = blockIdx.x;                // natural order: consecutive blocks share layer
    const int l    = bid >> 6;
    const int tile = bid & 63;
    const float* xg = x + ((size_t)l * T_N + tile * BM) * K_N;
    const unsigned short* wl = wf + (size_t)l * (N_N * K_N);

    // stage x: flat coalesced float4 reads -> bf16 -> swizzled 8B LDS writes (R1-verified)
    #pragma unroll
    for (int i = 0; i < 8; ++i) {
        int f = i * 512 + tid;                  // float4 index
        const float4 v = ((const float4*)xg)[f];
        int row = f >> 5;
        int kc  = (f & 31) * 4;
        union { unsigned short s[4]; unsigned long long u; } p;
        p.s[0] = f2bf(v.x); p.s[1] = f2bf(v.y); p.s[2] = f2bf(v.z); p.s[3] = f2bf(v.w);
        int us = (row * K_N + kc) ^ ((row & 7) << 3);
        *(unsigned long long*)&xs[us] = p.u;
    }
    // stage w: linear 32KB copy, lane-consecutive 16B (conflict-free both sides)
    #pragma unroll
    for (int i = 0; i < 4; ++i) {
        int c = i * 512 + tid;
        ((short8*)wsh)[c] = ((const short8*)wl)[c];
    }
    __syncthreads();

    f32x4 acc[8];
    #pragma unroll
    for (int ni = 0; ni < 8; ++ni)
        acc[ni] = (f32x4){0.f, 0.f, 0.f, 0.f};

    const int tbase = wid * 16;
    #pragma unroll
    for (int kk = 0; kk < 4; ++kk) {
        const int row = tbase + lr;
        const short8 xb = *(const short8*)&xs[(row * K_N + kk * 32 + lg * 8) ^ ((row & 7) << 3)];
        short8 wv[8];
        #pragma unroll
        for (int ni = 0; ni < 8; ++ni)
            wv[ni] = ((const short8*)wsh)[(ni * 4 + kk) * 64 + lane];
        #pragma unroll
        for (int ni = 0; ni < 8; ++ni)
            acc[ni] = __builtin_amdgcn_mfma_f32_16x16x32_bf16(wv[ni], xb, acc[ni], 0, 0, 0);
    }

    // epilogue: bias -> swizzled LDS transpose -> contiguous 1KB/wave float4 stores
    const float* bl = bias + l * N_N;
    __syncthreads();                            // xs/wsh dead, recycle as fp32 buffer
    float4* osm = (float4*)smem;                // [128 rows][32 f4], f4-index XOR row&7
    #pragma unroll
    for (int ni = 0; ni < 8; ++ni) {
        const float4 bv = *(const float4*)(bl + ni * 16 + lg * 4);
        float4 r;
        r.x = acc[ni][0] + bv.x;
        r.y = acc[ni][1] + bv.y;
        r.z = acc[ni][2] + bv.z;
        r.w = acc[ni][3] + bv.w;
        const int row = tbase + lr;             // out row t (lane holds t = tbase+lr)
        const int cf4 = ni * 4 + lg;            // out col group (lane's 4 cols)
        osm[row * 32 + (cf4 ^ (row & 7))] = r;
    }
    __syncthreads();
    float4* og = (float4*)(out + ((size_t)l * T_N + tile * BM) * N_N);
    #pragma unroll
    for (int i = 0; i < 8; ++i) {
        int fi = i * 512 + tid;                 // flat f4 index: wave -> 1KB contiguous
        int row = fi >> 5, cf4 = fi & 31;
        og[fi] = osm[row * 32 + (cf4 ^ (row & 7))];
    }
}

extern "C" void kernel_launch(void* const* d_in, const int* in_sizes, int n_in,
                              void* d_out, int out_size, void* d_ws, size_t ws_size,
                              hipStream_t stream) {
    const float* x = (const float*)d_in[0];
    const float* w = (const float*)d_in[1];
    const float* b = (const float*)d_in[2];
    float* out = (float*)d_out;
    unsigned short* wf = (unsigned short*)d_ws;   // 2 MB scratch, rewritten every call

    wfrag_kernel<<<L_N, 256, 0, stream>>>(w, wf);
    gl_kernel<<<L_N * (T_N / BM), 512, 0, stream>>>(x, wf, b, out);
}